// Round 11
// baseline (1751.444 us; speedup 1.0000x reference)
//
#include <hip/hip_runtime.h>
#include <hip/hip_bf16.h>
#include <math.h>

// Problem: B=4, S=4096, D=1024.  M = B*S = 16384 rows.
//  k = fft(x@Wk^T + bk); v = fft(x@Wv^T+bv); q = fft(x@Wq^T+bq)
//  kv = cumsum(k*v, axis=S); queried = kv*conj(q); normalize over D; real(ifft)/sqrt(D)
//
// Spectral domain kept in BIT-REVERSED order throughout (DIF forward, DIT
// inverse) -> no bit-reversal permutations needed; all intermediate ops are
// permutation-invariant.
//
// Workspace budget: 202 MB used.
//   kvp  : [M][D] float2  = 134217728 B   (Kf, then Kf*Vf, then cumsum in place)
//   lin0 : [M][D] float   =  67108864 B   (reused for k-linear then v-linear)
//   cs   : [B][16][D] f2  =    524288 B   (scan chunk sums)
// q-linear lives in d_out (exactly M*D floats) and FFT(q) is recomputed in
// the final kernel, which reads its own row before overwriting it.

#define MROWS 16384
#define ND    1024
#define SLEN  4096
#define NB    4
#define CHUNKS 16
#define CHLEN  256

#define WS_KVP_BYTES  (134217728ull)
#define WS_LIN_BYTES  (67108864ull)
#define WS_CS_BYTES   (524288ull)
#define WS_NEEDED     (WS_KVP_BYTES + WS_LIN_BYTES + WS_CS_BYTES)

__device__ __forceinline__ float2 c_add(float2 a, float2 b) {
    return make_float2(a.x + b.x, a.y + b.y);
}
__device__ __forceinline__ float2 c_mul(float2 a, float2 b) {
    return make_float2(a.x * b.x - a.y * b.y, a.x * b.y + a.y * b.x);
}

// ---------------------------------------------------------------------------
// GEMM  out[m][n] = sum_k x[m][k]*W[n][k] + b[n]
// 128x128 tile, BK=8, 256 threads, 8x8 per thread, fp32 vector FMA.
// ---------------------------------------------------------------------------
__global__ __launch_bounds__(256) void gemm_kernel(
    const float* __restrict__ x,
    const float* __restrict__ Wm, const float* __restrict__ bias,
    float* __restrict__ out)
{
    const int K = ND, N = ND;
    const int bm = blockIdx.y * 128;
    const int bn = blockIdx.x * 128;
    const int tid = threadIdx.x;
    const int tx = tid & 15, ty = tid >> 4;

    __shared__ float As[8][128];
    __shared__ float Bs[8][128];

    const int lr = tid >> 1;          // row within tile (0..127)
    const int lc = (tid & 1) << 2;    // k offset 0 or 4

    float acc[8][8];
    #pragma unroll
    for (int i = 0; i < 8; i++)
        #pragma unroll
        for (int j = 0; j < 8; j++) acc[i][j] = 0.0f;

    const float* aptr = x  + (size_t)(bm + lr) * K + lc;
    const float* bptr = Wm + (size_t)(bn + lr) * K + lc;

    for (int k0 = 0; k0 < K; k0 += 8) {
        float4 av  = *(const float4*)(aptr + k0);
        float4 bv4 = *(const float4*)(bptr + k0);
        __syncthreads();
        As[lc + 0][lr] = av.x;  As[lc + 1][lr] = av.y;
        As[lc + 2][lr] = av.z;  As[lc + 3][lr] = av.w;
        Bs[lc + 0][lr] = bv4.x; Bs[lc + 1][lr] = bv4.y;
        Bs[lc + 2][lr] = bv4.z; Bs[lc + 3][lr] = bv4.w;
        __syncthreads();
        #pragma unroll
        for (int kk = 0; kk < 8; kk++) {
            float a[8], b[8];
            *(float4*)(a)     = *(const float4*)&As[kk][ty * 8];
            *(float4*)(a + 4) = *(const float4*)&As[kk][ty * 8 + 4];
            *(float4*)(b)     = *(const float4*)&Bs[kk][tx * 8];
            *(float4*)(b + 4) = *(const float4*)&Bs[kk][tx * 8 + 4];
            #pragma unroll
            for (int i = 0; i < 8; i++)
                #pragma unroll
                for (int j = 0; j < 8; j++)
                    acc[i][j] = fmaf(a[i], b[j], acc[i][j]);
        }
    }

    float bb[8];
    #pragma unroll
    for (int j = 0; j < 8; j++) bb[j] = bias[bn + tx * 8 + j];
    #pragma unroll
    for (int i = 0; i < 8; i++) {
        float4 v0 = make_float4(acc[i][0] + bb[0], acc[i][1] + bb[1],
                                acc[i][2] + bb[2], acc[i][3] + bb[3]);
        float4 v1 = make_float4(acc[i][4] + bb[4], acc[i][5] + bb[5],
                                acc[i][6] + bb[6], acc[i][7] + bb[7]);
        float* orow = out + (size_t)(bm + ty * 8 + i) * N + bn + tx * 8;
        *(float4*)(orow)     = v0;
        *(float4*)(orow + 4) = v1;
    }
}

// ---------------------------------------------------------------------------
// Forward FFT, radix-2 DIF: natural-order input -> bit-reversed-order output.
// 512 threads, length 1024, in LDS. twid[j] = exp(-2*pi*i*j/1024), j<512.
// ---------------------------------------------------------------------------
__device__ __forceinline__ void fft_forward_dif(const float* __restrict__ src,
                                                float2* buf,
                                                const float2* twid)
{
    const int tid = threadIdx.x;
    buf[tid]       = make_float2(src[tid], 0.0f);
    buf[tid + 512] = make_float2(src[tid + 512], 0.0f);
    for (int s = 10; s >= 1; s--) {
        __syncthreads();
        const int half = 1 << (s - 1);
        const int j    = tid & (half - 1);
        const int base = ((tid >> (s - 1)) << s) + j;
        float2 a = buf[base];
        float2 b = buf[base + half];
        float2 w = twid[j << (10 - s)];
        float2 d = make_float2(a.x - b.x, a.y - b.y);
        buf[base]        = make_float2(a.x + b.x, a.y + b.y);
        buf[base + half] = make_float2(d.x * w.x - d.y * w.y,
                                       d.x * w.y + d.y * w.x);
    }
    __syncthreads();
}

// ---------------------------------------------------------------------------
// FFT of k-linear rows -> store Kf into kvp.
// ---------------------------------------------------------------------------
__global__ __launch_bounds__(512) void fftK_kernel(const float* __restrict__ lin0,
                                                   float2* __restrict__ kvp)
{
    __shared__ float2 buf[1024];
    __shared__ float2 twid[512];
    const int tid = threadIdx.x;
    const size_t row = blockIdx.x;

    float ang = -6.283185307179586f * (float)tid * (1.0f / 1024.0f);
    float sv, cv;
    sincosf(ang, &sv, &cv);
    twid[tid] = make_float2(cv, sv);
    // first __syncthreads inside fft_forward_dif covers this write

    fft_forward_dif(lin0 + row * ND, buf, twid);
    kvp[row * ND + tid]       = buf[tid];
    kvp[row * ND + tid + 512] = buf[tid + 512];
}

// ---------------------------------------------------------------------------
// FFT of v-linear rows; kvp := kvp * Vf  (in place).
// ---------------------------------------------------------------------------
__global__ __launch_bounds__(512) void fftV_kernel(const float* __restrict__ lin0,
                                                   float2* __restrict__ kvp)
{
    __shared__ float2 buf[1024];
    __shared__ float2 twid[512];
    const int tid = threadIdx.x;
    const size_t row = blockIdx.x;

    float ang = -6.283185307179586f * (float)tid * (1.0f / 1024.0f);
    float sv, cv;
    sincosf(ang, &sv, &cv);
    twid[tid] = make_float2(cv, sv);

    fft_forward_dif(lin0 + row * ND, buf, twid);
    float2 k0 = kvp[row * ND + tid];
    float2 k1 = kvp[row * ND + tid + 512];
    kvp[row * ND + tid]       = c_mul(k0, buf[tid]);
    kvp[row * ND + tid + 512] = c_mul(k1, buf[tid + 512]);
}

// ---------------------------------------------------------------------------
// Kernels 3a/3b/3c: chunked inclusive scan of kvp along S (per b, per d).
// ---------------------------------------------------------------------------
__global__ __launch_bounds__(256) void scan_chunk_kernel(const float2* __restrict__ kvp,
                                                         float2* __restrict__ cs)
{
    const int d = blockIdx.x * 256 + threadIdx.x;
    const int c = blockIdx.y;
    const int b = blockIdx.z;
    float2 acc = make_float2(0.f, 0.f);
    size_t base = ((size_t)b * SLEN + (size_t)c * CHLEN) * ND + d;
    for (int i = 0; i < CHLEN; i++) {
        acc = c_add(acc, kvp[base + (size_t)i * ND]);
    }
    cs[((size_t)b * CHUNKS + c) * ND + d] = acc;
}

__global__ __launch_bounds__(256) void scan_prefix_kernel(float2* __restrict__ cs)
{
    const int d = blockIdx.x * 256 + threadIdx.x;
    const int b = blockIdx.y;
    float2 run = make_float2(0.f, 0.f);
    for (int c = 0; c < CHUNKS; c++) {
        size_t idx = ((size_t)b * CHUNKS + c) * ND + d;
        float2 t = cs[idx];
        cs[idx] = run;          // exclusive prefix
        run = c_add(run, t);
    }
}

__global__ __launch_bounds__(256) void scan_apply_kernel(float2* __restrict__ kvp,
                                                         const float2* __restrict__ cs)
{
    const int d = blockIdx.x * 256 + threadIdx.x;
    const int c = blockIdx.y;
    const int b = blockIdx.z;
    float2 run = cs[((size_t)b * CHUNKS + c) * ND + d];
    size_t base = ((size_t)b * SLEN + (size_t)c * CHLEN) * ND + d;
    for (int i = 0; i < CHLEN; i++) {
        size_t idx = base + (size_t)i * ND;
        run = c_add(run, kvp[idx]);
        kvp[idx] = run;         // in-place -> inclusive cumsum
    }
}

// ---------------------------------------------------------------------------
// Final: q-linear row lives in `out`; FFT it (DIF), u = kvcum*conj(Qf),
// L2-normalize over D, inverse FFT (DIT, bit-reversed -> natural),
// out = real * (1/1024) * (1/32) -- ifft scale and 1/sqrt(D).
// ---------------------------------------------------------------------------
__global__ __launch_bounds__(512) void final_kernel(const float2* __restrict__ kvc,
                                                    float* __restrict__ out)
{
    __shared__ float2 buf[1024];
    __shared__ float2 twid[512];
    __shared__ float red[8];
    const int tid = threadIdx.x;
    const size_t row = blockIdx.x;

    float ang = -6.283185307179586f * (float)tid * (1.0f / 1024.0f);
    float sv, cv;
    sincosf(ang, &sv, &cv);
    twid[tid] = make_float2(cv, sv);

    // forward FFT of the q-linear row (stored in out)
    fft_forward_dif(out + row * ND, buf, twid);
    float2 q0 = buf[tid];
    float2 q1 = buf[tid + 512];

    float2 kv0 = kvc[row * ND + tid];
    float2 kv1 = kvc[row * ND + tid + 512];
    float2 u0 = c_mul(kv0, make_float2(q0.x, -q0.y));
    float2 u1 = c_mul(kv1, make_float2(q1.x, -q1.y));

    float p = u0.x * u0.x + u0.y * u0.y + u1.x * u1.x + u1.y * u1.y;
    #pragma unroll
    for (int off = 32; off >= 1; off >>= 1) p += __shfl_xor(p, off, 64);
    __syncthreads();               // buf reads from fft done before overwrite
    if ((tid & 63) == 0) red[tid >> 6] = p;
    buf[tid]       = u0;
    buf[tid + 512] = u1;
    __syncthreads();
    float ssum = 0.0f;
    #pragma unroll
    for (int i = 0; i < 8; i++) ssum += red[i];
    // scale = 1/(1e-9+nrm) * (1/N for ifft) * (1/sqrt(D))
    const float scale = 1.0f / (1e-9f + sqrtf(ssum)) * (1.0f / 32768.0f);

    // inverse DIT, bit-reversed input, twiddles conj(twid)
    for (int s = 1; s <= 10; s++) {
        __syncthreads();
        const int half = 1 << (s - 1);
        const int j    = tid & (half - 1);
        const int base = ((tid >> (s - 1)) << s) + j;
        float2 a = buf[base];
        float2 b = buf[base + half];
        float2 w = twid[j << (10 - s)];
        // t = b * conj(w)
        float2 t = make_float2(b.x * w.x + b.y * w.y, b.y * w.x - b.x * w.y);
        buf[base]        = c_add(a, t);
        buf[base + half] = make_float2(a.x - t.x, a.y - t.y);
    }
    __syncthreads();
    out[row * ND + tid]       = buf[tid].x * scale;
    out[row * ND + tid + 512] = buf[tid + 512].x * scale;
}

// ---------------------------------------------------------------------------
// Diagnostic: workspace too small -> make absmax show ws_size (no crash).
// ---------------------------------------------------------------------------
__global__ void ws_diag_kernel(float* __restrict__ out, float wsz)
{
    if (threadIdx.x == 0 && blockIdx.x == 0) out[0] = wsz;
}

// ---------------------------------------------------------------------------
extern "C" void kernel_launch(void* const* d_in, const int* in_sizes, int n_in,
                              void* d_out, int out_size, void* d_ws, size_t ws_size,
                              hipStream_t stream)
{
    const float* x  = (const float*)d_in[0];
    const float* Wk = (const float*)d_in[1];
    const float* bk = (const float*)d_in[2];
    const float* Wv = (const float*)d_in[3];
    const float* bv = (const float*)d_in[4];
    const float* Wq = (const float*)d_in[5];
    const float* bq = (const float*)d_in[6];
    float* out = (float*)d_out;

    if (ws_size < WS_NEEDED) {
        ws_diag_kernel<<<1, 64, 0, stream>>>(out, (float)ws_size);
        return;
    }

    char* ws = (char*)d_ws;
    float2* kvp  = (float2*)ws;                                  // 134217728 B
    float*  lin0 = (float*)(ws + WS_KVP_BYTES);                  //  67108864 B
    float2* cs   = (float2*)(ws + WS_KVP_BYTES + WS_LIN_BYTES);  //    524288 B

    // q projection -> d_out (used as scratch; final kernel re-reads it)
    gemm_kernel<<<dim3(8, 128), 256, 0, stream>>>(x, Wq, bq, out);
    // k projection -> lin0; FFT -> kvp
    gemm_kernel<<<dim3(8, 128), 256, 0, stream>>>(x, Wk, bk, lin0);
    fftK_kernel<<<dim3(MROWS), 512, 0, stream>>>(lin0, kvp);
    // v projection -> lin0 (reused); FFT and multiply in place
    gemm_kernel<<<dim3(8, 128), 256, 0, stream>>>(x, Wv, bv, lin0);
    fftV_kernel<<<dim3(MROWS), 512, 0, stream>>>(lin0, kvp);
    // causal cumsum along S
    scan_chunk_kernel<<<dim3(4, CHUNKS, NB), 256, 0, stream>>>(kvp, cs);
    scan_prefix_kernel<<<dim3(4, NB), 256, 0, stream>>>(cs);
    scan_apply_kernel<<<dim3(4, CHUNKS, NB), 256, 0, stream>>>(kvp, cs);
    // unbind + normalize + ifft
    final_kernel<<<dim3(MROWS), 512, 0, stream>>>(kvp, out);
}

// Round 14
// 882.755 us; speedup vs baseline: 1.9841x; 1.9841x over previous
//
#include <hip/hip_runtime.h>
#include <hip/hip_bf16.h>
#include <math.h>

// Problem: B=4, S=4096, D=1024.  M = B*S = 16384 rows.
//  k = fft(x@Wk^T + bk); v = fft(x@Wv^T+bv); q = fft(x@Wq^T+bq)
//  kv = cumsum(k*v, axis=S); queried = kv*conj(q); normalize over D; real(ifft)/sqrt(D)
//
// R11 -> R12 change: gemm_kernel rewritten from fp32 vector FMA (measured 75 TF,
// 1385 us for 3 launches) to bf16 hi/lo-split MFMA (16x16x32):
//   x = xh + xl, W = wh + wl (bf16 each);  C ~= xh@wh + xh@wl + xl@wh
// Split error ~2^-15 relative -> output abs error ~1e-8 (threshold 3.3e-6).
// Everything else (FFT/scan/final, buffers, launch order) is byte-identical.
//
// Workspace budget: 202 MB (validated on HW in R11).
//   kvp  : [M][D] float2  = 134217728 B
//   lin0 : [M][D] float   =  67108864 B
//   cs   : [B][16][D] f2  =    524288 B

#define MROWS 16384
#define ND    1024
#define SLEN  4096
#define NB    4
#define CHUNKS 16
#define CHLEN  256

#define WS_KVP_BYTES  (134217728ull)
#define WS_LIN_BYTES  (67108864ull)
#define WS_CS_BYTES   (524288ull)
#define WS_NEEDED     (WS_KVP_BYTES + WS_LIN_BYTES + WS_CS_BYTES)

typedef __attribute__((ext_vector_type(8))) short short8v;
typedef __attribute__((ext_vector_type(4))) float f32x4;

__device__ __forceinline__ float2 c_add(float2 a, float2 b) {
    return make_float2(a.x + b.x, a.y + b.y);
}
__device__ __forceinline__ float2 c_mul(float2 a, float2 b) {
    return make_float2(a.x * b.x - a.y * b.y, a.x * b.y + a.y * b.x);
}

// Split two fp32 into packed bf16 hi pair + bf16 lo pair.
// hi = top 16 bits (truncation); lo = f - hi (exact in fp32), truncated to bf16.
__device__ __forceinline__ void split2(float f0, float f1,
                                       unsigned& hp, unsigned& lp)
{
    unsigned u0 = __float_as_uint(f0), u1 = __float_as_uint(f1);
    unsigned h0 = u0 & 0xFFFF0000u,  h1 = u1 & 0xFFFF0000u;
    float l0 = f0 - __uint_as_float(h0);
    float l1 = f1 - __uint_as_float(h1);
    hp = (u0 >> 16) | h1;
    lp = (__float_as_uint(l0) >> 16) | (__float_as_uint(l1) & 0xFFFF0000u);
}

// ---------------------------------------------------------------------------
// GEMM  out[m][n] = sum_k x[m][k]*W[n][k] + b[n]   (M=16384, N=K=1024)
// 128x128 tile, BK=32, 256 threads = 4 waves (2x2 of 64x64 quadrants),
// mfma_f32_16x16x32_bf16 with hi/lo split (3 products / fragment pair).
// LDS layout [kc][row][8] bf16: fragment ds_read_b128 is conflict-free
// (64 lanes hit 64 distinct 16B slots).
// Fragment maps (guide §3, m89/m91-verified): A: m=lane&15, k=(lane>>4)*8+j;
// B: n=lane&15, k=(lane>>4)*8+j; D: n=lane&15, m=(lane>>4)*4+reg.
// ---------------------------------------------------------------------------
__global__ __launch_bounds__(256) void gemm_kernel(
    const float* __restrict__ x,
    const float* __restrict__ Wm, const float* __restrict__ bias,
    float* __restrict__ out)
{
    const int bm = blockIdx.y * 128;
    const int bn = blockIdx.x * 128;
    const int tid  = threadIdx.x;
    const int lane = tid & 63;
    const int wid  = tid >> 6;
    const int wr = wid >> 1, wc = wid & 1;     // wave quadrant (2x2 of 64x64)

    __shared__ __align__(16) short Ah[4][128][8];
    __shared__ __align__(16) short Al[4][128][8];
    __shared__ __align__(16) short Bh[4][128][8];
    __shared__ __align__(16) short Bl[4][128][8];

    f32x4 acc[4][4];
    #pragma unroll
    for (int i = 0; i < 4; i++)
        #pragma unroll
        for (int j = 0; j < 4; j++)
            acc[i][j] = (f32x4){0.f, 0.f, 0.f, 0.f};

    const int r   = tid >> 1;          // staging row 0..127
    const int kh  = (tid & 1) * 16;    // k offset 0 or 16 within BK=32
    const int kc0 = kh >> 3;           // LDS k-chunk 0 or 2

    const int kg = lane >> 4;          // fragment k-group 0..3
    const int fr = lane & 15;          // fragment row/col index

    for (int k0 = 0; k0 < 1024; k0 += 32) {
        // ---- load fp32 staging data (registers only; before barrier)
        const float* xs = x  + (size_t)(bm + r) * 1024 + k0 + kh;
        const float* wp = Wm + (size_t)(bn + r) * 1024 + k0 + kh;
        float fa[16], fb[16];
        #pragma unroll
        for (int q = 0; q < 4; q++) {
            *(float4*)&fa[q * 4] = *(const float4*)(xs + q * 4);
            *(float4*)&fb[q * 4] = *(const float4*)(wp + q * 4);
        }

        __syncthreads();   // previous iteration's fragment reads done

        unsigned ha[8], la[8], hb[8], lb[8];
        #pragma unroll
        for (int q = 0; q < 8; q++) {
            split2(fa[2*q], fa[2*q+1], ha[q], la[q]);
            split2(fb[2*q], fb[2*q+1], hb[q], lb[q]);
        }
        *(uint4*)&Ah[kc0    ][r][0] = make_uint4(ha[0], ha[1], ha[2], ha[3]);
        *(uint4*)&Ah[kc0 + 1][r][0] = make_uint4(ha[4], ha[5], ha[6], ha[7]);
        *(uint4*)&Al[kc0    ][r][0] = make_uint4(la[0], la[1], la[2], la[3]);
        *(uint4*)&Al[kc0 + 1][r][0] = make_uint4(la[4], la[5], la[6], la[7]);
        *(uint4*)&Bh[kc0    ][r][0] = make_uint4(hb[0], hb[1], hb[2], hb[3]);
        *(uint4*)&Bh[kc0 + 1][r][0] = make_uint4(hb[4], hb[5], hb[6], hb[7]);
        *(uint4*)&Bl[kc0    ][r][0] = make_uint4(lb[0], lb[1], lb[2], lb[3]);
        *(uint4*)&Bl[kc0 + 1][r][0] = make_uint4(lb[4], lb[5], lb[6], lb[7]);

        __syncthreads();   // tiles staged

        // ---- fragments + MFMA
        short8v a_h[4], a_l[4], b_h[4], b_l[4];
        #pragma unroll
        for (int i = 0; i < 4; i++) {
            a_h[i] = *(const short8v*)&Ah[kg][wr * 64 + i * 16 + fr][0];
            a_l[i] = *(const short8v*)&Al[kg][wr * 64 + i * 16 + fr][0];
            b_h[i] = *(const short8v*)&Bh[kg][wc * 64 + i * 16 + fr][0];
            b_l[i] = *(const short8v*)&Bl[kg][wc * 64 + i * 16 + fr][0];
        }
        #pragma unroll
        for (int i = 0; i < 4; i++)
            #pragma unroll
            for (int j = 0; j < 4; j++) {
                acc[i][j] = __builtin_amdgcn_mfma_f32_16x16x32_bf16(
                                a_h[i], b_h[j], acc[i][j], 0, 0, 0);
                acc[i][j] = __builtin_amdgcn_mfma_f32_16x16x32_bf16(
                                a_h[i], b_l[j], acc[i][j], 0, 0, 0);
                acc[i][j] = __builtin_amdgcn_mfma_f32_16x16x32_bf16(
                                a_l[i], b_h[j], acc[i][j], 0, 0, 0);
            }
    }

    // ---- epilogue: D frag n=lane&15, m=(lane>>4)*4+reg
    const int rg = (lane >> 4) * 4;
    #pragma unroll
    for (int i = 0; i < 4; i++) {
        const size_t row0 = (size_t)(bm + wr * 64 + i * 16 + rg);
        #pragma unroll
        for (int j = 0; j < 4; j++) {
            const int col = bn + wc * 64 + j * 16 + fr;
            const float bb = bias[col];
            float* o = out + row0 * 1024 + col;
            o[0]        = acc[i][j][0] + bb;
            o[1024]     = acc[i][j][1] + bb;
            o[2048]     = acc[i][j][2] + bb;
            o[3072]     = acc[i][j][3] + bb;
        }
    }
}

// ---------------------------------------------------------------------------
// Forward FFT, radix-2 DIF: natural-order input -> bit-reversed-order output.
// 512 threads, length 1024, in LDS. twid[j] = exp(-2*pi*i*j/1024), j<512.
// ---------------------------------------------------------------------------
__device__ __forceinline__ void fft_forward_dif(const float* __restrict__ src,
                                                float2* buf,
                                                const float2* twid)
{
    const int tid = threadIdx.x;
    buf[tid]       = make_float2(src[tid], 0.0f);
    buf[tid + 512] = make_float2(src[tid + 512], 0.0f);
    for (int s = 10; s >= 1; s--) {
        __syncthreads();
        const int half = 1 << (s - 1);
        const int j    = tid & (half - 1);
        const int base = ((tid >> (s - 1)) << s) + j;
        float2 a = buf[base];
        float2 b = buf[base + half];
        float2 w = twid[j << (10 - s)];
        float2 d = make_float2(a.x - b.x, a.y - b.y);
        buf[base]        = make_float2(a.x + b.x, a.y + b.y);
        buf[base + half] = make_float2(d.x * w.x - d.y * w.y,
                                       d.x * w.y + d.y * w.x);
    }
    __syncthreads();
}

// ---------------------------------------------------------------------------
// FFT of k-linear rows -> store Kf into kvp.
// ---------------------------------------------------------------------------
__global__ __launch_bounds__(512) void fftK_kernel(const float* __restrict__ lin0,
                                                   float2* __restrict__ kvp)
{
    __shared__ float2 buf[1024];
    __shared__ float2 twid[512];
    const int tid = threadIdx.x;
    const size_t row = blockIdx.x;

    float ang = -6.283185307179586f * (float)tid * (1.0f / 1024.0f);
    float sv, cv;
    sincosf(ang, &sv, &cv);
    twid[tid] = make_float2(cv, sv);
    // first __syncthreads inside fft_forward_dif covers this write

    fft_forward_dif(lin0 + row * ND, buf, twid);
    kvp[row * ND + tid]       = buf[tid];
    kvp[row * ND + tid + 512] = buf[tid + 512];
}

// ---------------------------------------------------------------------------
// FFT of v-linear rows; kvp := kvp * Vf  (in place).
// ---------------------------------------------------------------------------
__global__ __launch_bounds__(512) void fftV_kernel(const float* __restrict__ lin0,
                                                   float2* __restrict__ kvp)
{
    __shared__ float2 buf[1024];
    __shared__ float2 twid[512];
    const int tid = threadIdx.x;
    const size_t row = blockIdx.x;

    float ang = -6.283185307179586f * (float)tid * (1.0f / 1024.0f);
    float sv, cv;
    sincosf(ang, &sv, &cv);
    twid[tid] = make_float2(cv, sv);

    fft_forward_dif(lin0 + row * ND, buf, twid);
    float2 k0 = kvp[row * ND + tid];
    float2 k1 = kvp[row * ND + tid + 512];
    kvp[row * ND + tid]       = c_mul(k0, buf[tid]);
    kvp[row * ND + tid + 512] = c_mul(k1, buf[tid + 512]);
}

// ---------------------------------------------------------------------------
// Kernels 3a/3b/3c: chunked inclusive scan of kvp along S (per b, per d).
// ---------------------------------------------------------------------------
__global__ __launch_bounds__(256) void scan_chunk_kernel(const float2* __restrict__ kvp,
                                                         float2* __restrict__ cs)
{
    const int d = blockIdx.x * 256 + threadIdx.x;
    const int c = blockIdx.y;
    const int b = blockIdx.z;
    float2 acc = make_float2(0.f, 0.f);
    size_t base = ((size_t)b * SLEN + (size_t)c * CHLEN) * ND + d;
    for (int i = 0; i < CHLEN; i++) {
        acc = c_add(acc, kvp[base + (size_t)i * ND]);
    }
    cs[((size_t)b * CHUNKS + c) * ND + d] = acc;
}

__global__ __launch_bounds__(256) void scan_prefix_kernel(float2* __restrict__ cs)
{
    const int d = blockIdx.x * 256 + threadIdx.x;
    const int b = blockIdx.y;
    float2 run = make_float2(0.f, 0.f);
    for (int c = 0; c < CHUNKS; c++) {
        size_t idx = ((size_t)b * CHUNKS + c) * ND + d;
        float2 t = cs[idx];
        cs[idx] = run;          // exclusive prefix
        run = c_add(run, t);
    }
}

__global__ __launch_bounds__(256) void scan_apply_kernel(float2* __restrict__ kvp,
                                                         const float2* __restrict__ cs)
{
    const int d = blockIdx.x * 256 + threadIdx.x;
    const int c = blockIdx.y;
    const int b = blockIdx.z;
    float2 run = cs[((size_t)b * CHUNKS + c) * ND + d];
    size_t base = ((size_t)b * SLEN + (size_t)c * CHLEN) * ND + d;
    for (int i = 0; i < CHLEN; i++) {
        size_t idx = base + (size_t)i * ND;
        run = c_add(run, kvp[idx]);
        kvp[idx] = run;         // in-place -> inclusive cumsum
    }
}

// ---------------------------------------------------------------------------
// Final: q-linear row lives in `out`; FFT it (DIF), u = kvcum*conj(Qf),
// L2-normalize over D, inverse FFT (DIT, bit-reversed -> natural),
// out = real * (1/1024) * (1/32) -- ifft scale and 1/sqrt(D).
// ---------------------------------------------------------------------------
__global__ __launch_bounds__(512) void final_kernel(const float2* __restrict__ kvc,
                                                    float* __restrict__ out)
{
    __shared__ float2 buf[1024];
    __shared__ float2 twid[512];
    __shared__ float red[8];
    const int tid = threadIdx.x;
    const size_t row = blockIdx.x;

    float ang = -6.283185307179586f * (float)tid * (1.0f / 1024.0f);
    float sv, cv;
    sincosf(ang, &sv, &cv);
    twid[tid] = make_float2(cv, sv);

    // forward FFT of the q-linear row (stored in out)
    fft_forward_dif(out + row * ND, buf, twid);
    float2 q0 = buf[tid];
    float2 q1 = buf[tid + 512];

    float2 kv0 = kvc[row * ND + tid];
    float2 kv1 = kvc[row * ND + tid + 512];
    float2 u0 = c_mul(kv0, make_float2(q0.x, -q0.y));
    float2 u1 = c_mul(kv1, make_float2(q1.x, -q1.y));

    float p = u0.x * u0.x + u0.y * u0.y + u1.x * u1.x + u1.y * u1.y;
    #pragma unroll
    for (int off = 32; off >= 1; off >>= 1) p += __shfl_xor(p, off, 64);
    __syncthreads();               // buf reads from fft done before overwrite
    if ((tid & 63) == 0) red[tid >> 6] = p;
    buf[tid]       = u0;
    buf[tid + 512] = u1;
    __syncthreads();
    float ssum = 0.0f;
    #pragma unroll
    for (int i = 0; i < 8; i++) ssum += red[i];
    // scale = 1/(1e-9+nrm) * (1/N for ifft) * (1/sqrt(D))
    const float scale = 1.0f / (1e-9f + sqrtf(ssum)) * (1.0f / 32768.0f);

    // inverse DIT, bit-reversed input, twiddles conj(twid)
    for (int s = 1; s <= 10; s++) {
        __syncthreads();
        const int half = 1 << (s - 1);
        const int j    = tid & (half - 1);
        const int base = ((tid >> (s - 1)) << s) + j;
        float2 a = buf[base];
        float2 b = buf[base + half];
        float2 w = twid[j << (10 - s)];
        // t = b * conj(w)
        float2 t = make_float2(b.x * w.x + b.y * w.y, b.y * w.x - b.x * w.y);
        buf[base]        = c_add(a, t);
        buf[base + half] = make_float2(a.x - t.x, a.y - t.y);
    }
    __syncthreads();
    out[row * ND + tid]       = buf[tid].x * scale;
    out[row * ND + tid + 512] = buf[tid + 512].x * scale;
}

// ---------------------------------------------------------------------------
// Diagnostic: workspace too small -> make absmax show ws_size (no crash).
// ---------------------------------------------------------------------------
__global__ void ws_diag_kernel(float* __restrict__ out, float wsz)
{
    if (threadIdx.x == 0 && blockIdx.x == 0) out[0] = wsz;
}

// ---------------------------------------------------------------------------
extern "C" void kernel_launch(void* const* d_in, const int* in_sizes, int n_in,
                              void* d_out, int out_size, void* d_ws, size_t ws_size,
                              hipStream_t stream)
{
    const float* x  = (const float*)d_in[0];
    const float* Wk = (const float*)d_in[1];
    const float* bk = (const float*)d_in[2];
    const float* Wv = (const float*)d_in[3];
    const float* bv = (const float*)d_in[4];
    const float* Wq = (const float*)d_in[5];
    const float* bq = (const float*)d_in[6];
    float* out = (float*)d_out;

    if (ws_size < WS_NEEDED) {
        ws_diag_kernel<<<1, 64, 0, stream>>>(out, (float)ws_size);
        return;
    }

    char* ws = (char*)d_ws;
    float2* kvp  = (float2*)ws;                                  // 134217728 B
    float*  lin0 = (float*)(ws + WS_KVP_BYTES);                  //  67108864 B
    float2* cs   = (float2*)(ws + WS_KVP_BYTES + WS_LIN_BYTES);  //    524288 B

    // q projection -> d_out (used as scratch; final kernel re-reads it)
    gemm_kernel<<<dim3(8, 128), 256, 0, stream>>>(x, Wq, bq, out);
    // k projection -> lin0; FFT -> kvp
    gemm_kernel<<<dim3(8, 128), 256, 0, stream>>>(x, Wk, bk, lin0);
    fftK_kernel<<<dim3(MROWS), 512, 0, stream>>>(lin0, kvp);
    // v projection -> lin0 (reused); FFT and multiply in place
    gemm_kernel<<<dim3(8, 128), 256, 0, stream>>>(x, Wv, bv, lin0);
    fftV_kernel<<<dim3(MROWS), 512, 0, stream>>>(lin0, kvp);
    // causal cumsum along S
    scan_chunk_kernel<<<dim3(4, CHUNKS, NB), 256, 0, stream>>>(kvp, cs);
    scan_prefix_kernel<<<dim3(4, NB), 256, 0, stream>>>(cs);
    scan_apply_kernel<<<dim3(4, CHUNKS, NB), 256, 0, stream>>>(kvp, cs);
    // unbind + normalize + ifft
    final_kernel<<<dim3(MROWS), 512, 0, stream>>>(kvp, out);
}